// Round 12
// baseline (2355.241 us; speedup 1.0000x reference)
//
#include <hip/hip_runtime.h>
#include <math.h>

#define B_ 4
#define S_ 4096
#define D_ 768
#define U_ 64
#define TK 32
#define NT (S_ / TK)
#define XT_TILE (TK * D_)   // 24576 elems (48KB) per key-tile, B-fragment-ordered
#define QK_TILE 2048        // per 32-row q/k tile: 4 frags x 64 lanes x 8 elems

typedef __attribute__((ext_vector_type(8))) short short8;
typedef __attribute__((ext_vector_type(16))) float f32x16;

__device__ __forceinline__ unsigned short f2bf(float f) {
    unsigned int x = __float_as_uint(f);
    unsigned int r = (x + 0x7fffu + ((x >> 16) & 1u)) >> 16;
    return (unsigned short)r;
}

// ---------------- kernel 1: decode mask -> q-mask float + key bias float ----------------
__global__ __launch_bounds__(256) void decode_mask_k(const unsigned char* __restrict__ mraw,
                                                     float* __restrict__ maskf,
                                                     float* __restrict__ biasf) {
    int base = threadIdx.x * 4;
    int bad = (mraw[base + 1] | mraw[base + 2] | mraw[base + 3]) != 0;
    int isbyte = __syncthreads_or(bad);
    int i = blockIdx.x * 256 + threadIdx.x;
    if (i < B_ * S_) {
        int v = isbyte ? (int)mraw[i] : ((const int*)mraw)[i];
        maskf[i] = (v != 0) ? 1.0f : 0.0f;
        biasf[i] = (v != 0) ? 0.0f : -1e30f;
    }
}

// ------- kernel 2: q/k projection -> bf16 32x32x16 A/B fragments per 32-row tile -------
__global__ __launch_bounds__(256) void proj_qk_k(const float* __restrict__ x,
                                                 const float* __restrict__ Wq,
                                                 const float* __restrict__ Wk,
                                                 unsigned short* __restrict__ qg,
                                                 unsigned short* __restrict__ kg) {
    __shared__ float xs[16][D_];
    const int rbase = blockIdx.x * 16;
    const float4* xsrc = (const float4*)(x + (size_t)rbase * D_);
    float4* xdst = (float4*)&xs[0][0];
    for (int i = threadIdx.x; i < 16 * D_ / 4; i += 256) xdst[i] = xsrc[i];
    __syncthreads();

    const int c  = threadIdx.x & 127;
    const int rg = threadIdx.x >> 7;
    const float* __restrict__ W = (c < 64) ? Wq : Wk;
    const int u = c & 63;

    float acc[8] = {0.f, 0.f, 0.f, 0.f, 0.f, 0.f, 0.f, 0.f};
    #pragma unroll 4
    for (int d = 0; d < D_; ++d) {
        const float wv = W[d * U_ + u];
        #pragma unroll
        for (int r = 0; r < 8; ++r) acc[r] = fmaf(xs[rg * 8 + r][d], wv, acc[r]);
    }

    const int m  = u >> 4;
    const int b3 = (u >> 3) & 1;
    const int e  = u & 7;
    const int row0 = rbase + rg * 8;
    unsigned short* dst = ((c < 64) ? qg : kg)
        + (size_t)(row0 >> 5) * QK_TILE
        + ((m * 64) + (row0 & 31) + 32 * b3) * 8 + e;
    #pragma unroll
    for (int r = 0; r < 8; ++r) dst[r * 8] = f2bf(acc[r]);
}

// ---------------- kernel 3: x -> xT B-fragments, per (b, key-tile) ----------------
__global__ __launch_bounds__(512) void xpose_k(const float* __restrict__ x,
                                               unsigned short* __restrict__ xTg) {
    __shared__ float xs[TK][D_ + 4];
    const int tid = threadIdx.x;
    const int bt  = blockIdx.x;             // b*128 + kt
    const int s0  = (bt & 127) * TK;
    const int b   = bt >> 7;
    const float* xsrc = x + ((size_t)(b * S_ + s0)) * D_;
    const int r_ = tid >> 4, c_ = tid & 15;
    #pragma unroll
    for (int it = 0; it < 12; ++it) {
        const int col4 = c_ + it * 16;
        *(float4*)&xs[r_][col4 * 4] = *(const float4*)&xsrc[(size_t)r_ * D_ + col4 * 4];
    }
    __syncthreads();

    unsigned short* dst = xTg + (size_t)bt * XT_TILE;
    #pragma unroll
    for (int it = 0; it < 6; ++it) {
        const int cch = it * 512 + tid;
        const int col = cch & 31;
        const int kh  = (cch >> 5) & 1;
        const int db  = (cch >> 6) % 24;
        const int kw  = (cch >> 6) / 24;
        const int d   = db * 32 + col;
        const int sr  = kw * 16 + kh * 8;
        short8 v;
        #pragma unroll
        for (int e = 0; e < 8; ++e) v[e] = (short)f2bf(xs[sr + e][d]);
        *(short8*)&dst[cch * 8] = v;
    }
}

// ------- kernel 4: wave-autonomous flash, software-pipelined (PV one tile behind) -------
// wave = (qtile 32q, dg 192d). iter i: QK(t)+PV(t-1) MFMAs issue together; softmax(t)
// on VALU overlaps matrix pipe; xv(t)/k(t+1) reload has a full iteration of cover.
__global__ __launch_bounds__(512, 2) void attn_k(const unsigned short* __restrict__ xTg,
                                                 const unsigned short* __restrict__ qg,
                                                 const unsigned short* __restrict__ kg,
                                                 const float* __restrict__ maskf,
                                                 const float* __restrict__ biasf,
                                                 float* __restrict__ out) {
    __shared__ float sc_l[8][32];                            // per-wave rescale broadcast
    __shared__ __align__(16) unsigned short p_l[8][1024];    // per-wave p A-frags (2KB)

    const int tid = threadIdx.x;
    const int w = tid >> 6;
    const int l = tid & 63;
    const int hi = l >> 5;
    const int q5 = l & 31;
    // XCD remap: raw&7 -> (b, parity); each XCD's 32 blocks share one batch's xT
    // stream and march in rough lockstep from t0 = par*64.
    const int raw = blockIdx.x;
    const int bh = raw & 7;
    const int b = bh >> 1;
    const int par = bh & 1;
    const int qpair = (raw >> 3) * 2 + par;      // 0..63
    const int qtile = qpair * 2 + (w >> 2);      // 0..127
    const int dg = w & 3;
    const int bS = b * S_;
    const int q0 = qtile * 32;
    const int t0 = par * 64;

    const unsigned short* xT_b = xTg + (size_t)b * NT * XT_TILE;
    const unsigned short* kg_b = kg + (size_t)(b * NT) * QK_TILE;
    const float* bias_b = biasf + bS;
    unsigned short* pw = &p_l[w][0];

    // Q B-fragments (held whole kernel)
    short8 qf[4];
    {
        const unsigned short* qp = qg + (size_t)(b * NT + qtile) * QK_TILE;
        #pragma unroll
        for (int m = 0; m < 4; ++m) qf[m] = *(const short8*)(qp + (m * 64 + l) * 8);
    }

    f32x16 acc[6];
    {
        f32x16 z = {0.f};
        #pragma unroll
        for (int j = 0; j < 6; ++j) acc[j] = z;
    }
    float m_run = -1e30f, l_run = 0.f;

    // pipeline state
    short8 xvp[12];          // xT B-frags of the tile whose PV is pending
    short8 pf0p = {0}, pf1p = {0};   // p A-frags of the pending tile
    short8 kfA[4], kfB[4];

    auto load_k = [&](int tn, short8 (&kdst)[4]) {
        const unsigned short* kp = kg_b + (size_t)tn * QK_TILE;
        #pragma unroll
        for (int m = 0; m < 4; ++m) kdst[m] = *(const short8*)(kp + (m * 64 + l) * 8);
    };
    auto load_xv = [&](int tt) {
        const unsigned short* xt = xT_b + (size_t)tt * XT_TILE;
        #pragma unroll
        for (int kw = 0; kw < 2; ++kw)
            #pragma unroll
            for (int j = 0; j < 6; ++j)
                xvp[kw * 6 + j] = *(const short8*)(xt + ((kw * 24 + dg * 6 + j) * 64 + l) * 8);
    };
    auto pv = [&]() {
        #pragma unroll
        for (int j = 0; j < 6; ++j) {
            acc[j] = __builtin_amdgcn_mfma_f32_32x32x16_bf16(pf0p, xvp[j], acc[j], 0, 0, 0);
            acc[j] = __builtin_amdgcn_mfma_f32_32x32x16_bf16(pf1p, xvp[6 + j], acc[j], 0, 0, 0);
        }
    };
    auto qk = [&](short8 (&kcur)[4]) -> f32x16 {
        f32x16 c = {0.f};
        #pragma unroll
        for (int m = 0; m < 4; ++m)
            c = __builtin_amdgcn_mfma_f32_32x32x16_bf16(kcur[m], qf[m], c, 0, 0, 0);
        return c;
    };
    auto softmax_pack = [&](int tt, const f32x16& c) {
        const float* bt = bias_b + tt * TK;
        float4 b4[4];
        #pragma unroll
        for (int g = 0; g < 4; ++g) b4[g] = *(const float4*)(bt + g * 8 + hi * 4);
        float s[16];
        #pragma unroll
        for (int r = 0; r < 16; ++r)
            s[r] = fmaf(c[r], 0.125f, ((const float*)&b4[r >> 2])[r & 3]);
        float mx = s[0];
        #pragma unroll
        for (int r = 1; r < 16; ++r) mx = fmaxf(mx, s[r]);
        mx = fmaxf(mx, __shfl_xor(mx, 32));
        const bool upd = (mx > m_run + 8.f);   // defer-max (T13)
        if (__any(upd)) {
            float sc = 1.f;
            if (upd) { sc = __expf(m_run - mx); m_run = mx; }
            l_run *= sc;
            if (!hi) sc_l[w][q5] = sc;
            float4 scv[4];   // per-ROW (q) scale
            #pragma unroll
            for (int g = 0; g < 4; ++g) scv[g] = *(const float4*)&sc_l[w][g * 8 + hi * 4];
            #pragma unroll
            for (int j = 0; j < 6; ++j)
                #pragma unroll
                for (int r = 0; r < 16; ++r) acc[j][r] *= ((const float*)&scv[r >> 2])[r & 3];
        }
        float p[16], ps = 0.f;
        #pragma unroll
        for (int r = 0; r < 16; ++r) { p[r] = __expf(s[r] - m_run); ps += p[r]; }
        ps += __shfl_xor(ps, 32);
        l_run += ps;
        // pack p -> PV A-frags in wave-private LDS (same-wave ordering, no barrier)
        #pragma unroll
        for (int j = 0; j < 8; ++j) {
            const int r = j * 2;
            const unsigned int pk = (unsigned int)f2bf(p[r]) | ((unsigned int)f2bf(p[r + 1]) << 16);
            const int m_ = r >> 3;
            const int lp = q5 + 32 * ((r >> 2) & 1);
            const int by = ((r & 3) + 4 * hi) * 2;
            *(unsigned int*)((char*)pw + m_ * 1024 + lp * 16 + by) = pk;
        }
        pf0p = *(const short8*)(pw + l * 8);
        pf1p = *(const short8*)(pw + 512 + l * 8);
    };

    // body for tile tt: QK(tt) + PV(tt-1) issue together; then reload xv/k; softmax(tt)
    auto body = [&](int tt, int tn, short8 (&kcur)[4], short8 (&knxt)[4]) {
        const f32x16 c = qk(kcur);   // 4 MFMA (independent)
        pv();                        // 12 MFMA for previous tile (independent of softmax(tt))
        load_xv(tt);                 // WAR on xvp after pv(); full-iter latency cover
        load_k(tn, knxt);
        softmax_pack(tt, c);         // VALU chain overlaps matrix pipe; rescale after pv()
    };

    // ---- prologue: softmax(t0), no PV pending ----
    load_k(t0, kfA);
    {
        const f32x16 c0 = qk(kfA);
        softmax_pack(t0, c0);
        load_xv(t0);
        load_k((t0 + 1) & (NT - 1), kfB);
    }

    #define MSK (NT - 1)
    for (int it = 1; it + 1 < NT; it += 2) {
        body((t0 + it) & MSK, (t0 + it + 1) & MSK, kfB, kfA);
        body((t0 + it + 1) & MSK, (t0 + it + 2) & MSK, kfA, kfB);
    }
    body((t0 + NT - 1) & MSK, t0, kfB, kfA);   // it = 127 (prefetch wraps, harmless)
    pv();                                       // drain PV(last)
    #undef MSK

    // ---------- epilogue: inv broadcast, q-mask, store ----------
    {
        const float mq = maskf[bS + q0 + q5];
        const float inv = (mq > 0.f && l_run > 0.f) ? (1.f / l_run) : 0.f;
        if (!hi) sc_l[w][q5] = inv;
        float4 iv[4];
        #pragma unroll
        for (int g = 0; g < 4; ++g) iv[g] = *(const float4*)&sc_l[w][g * 8 + hi * 4];
        #pragma unroll
        for (int j = 0; j < 6; ++j) {
            const int dcol = dg * 192 + j * 32 + q5;
            #pragma unroll
            for (int r = 0; r < 16; ++r) {
                const int qr = (r & 3) + 8 * (r >> 2) + 4 * hi;
                out[(size_t)(bS + q0 + qr) * D_ + dcol] = acc[j][r] * ((const float*)&iv[r >> 2])[r & 3];
            }
        }
    }
}

extern "C" void kernel_launch(void* const* d_in, const int* in_sizes, int n_in,
                              void* d_out, int out_size, void* d_ws, size_t ws_size,
                              hipStream_t stream) {
    const float*         x    = (const float*)d_in[0];
    const unsigned char* mraw = (const unsigned char*)d_in[1];
    const float*         Wq   = (const float*)d_in[2];
    const float*         Wk   = (const float*)d_in[3];
    float*               outp = (float*)d_out;

    // ws: maskf f32 | biasf f32 | qg bf16 | kg bf16 | xTg bf16  (~28.1 MB)
    float* maskf = (float*)d_ws;
    float* biasf = maskf + (size_t)B_ * S_;
    unsigned short* qg  = (unsigned short*)(biasf + (size_t)B_ * S_);
    unsigned short* kg  = qg + (size_t)B_ * S_ * U_;
    unsigned short* xTg = kg + (size_t)B_ * S_ * U_;

    decode_mask_k<<<(B_ * S_) / 256, 256, 0, stream>>>(mraw, maskf, biasf);
    proj_qk_k<<<(B_ * S_) / 16, 256, 0, stream>>>(x, Wq, Wk, qg, kg);
    xpose_k<<<B_ * (S_ / TK), 512, 0, stream>>>(x, xTg);
    attn_k<<<256, 512, 0, stream>>>(xTg, qg, kg, maskf, biasf, outp);
}

// Round 13
// 309.165 us; speedup vs baseline: 7.6181x; 7.6181x over previous
//
#include <hip/hip_runtime.h>
#include <math.h>

#define B_ 4
#define S_ 4096
#define D_ 768
#define U_ 64
#define TK 32
#define NT (S_ / TK)
#define XT_TILE (TK * D_)   // 24576 elems (48KB) per key-tile, B-fragment-ordered
#define QK_TILE 2048        // per 32-row q/k tile: 4 frags x 64 lanes x 8 elems

typedef __attribute__((ext_vector_type(8))) short short8;
typedef __attribute__((ext_vector_type(16))) float f32x16;

__device__ __forceinline__ unsigned short f2bf(float f) {
    unsigned int x = __float_as_uint(f);
    unsigned int r = (x + 0x7fffu + ((x >> 16) & 1u)) >> 16;
    return (unsigned short)r;
}

// ---------------- kernel 1: decode mask -> q-mask float + key bias float ----------------
__global__ __launch_bounds__(256) void decode_mask_k(const unsigned char* __restrict__ mraw,
                                                     float* __restrict__ maskf,
                                                     float* __restrict__ biasf) {
    int base = threadIdx.x * 4;
    int bad = (mraw[base + 1] | mraw[base + 2] | mraw[base + 3]) != 0;
    int isbyte = __syncthreads_or(bad);
    int i = blockIdx.x * 256 + threadIdx.x;
    if (i < B_ * S_) {
        int v = isbyte ? (int)mraw[i] : ((const int*)mraw)[i];
        maskf[i] = (v != 0) ? 1.0f : 0.0f;
        biasf[i] = (v != 0) ? 0.0f : -1e30f;
    }
}

// ------- kernel 2: q/k projection -> bf16 32x32x16 A/B fragments per 32-row tile -------
__global__ __launch_bounds__(256) void proj_qk_k(const float* __restrict__ x,
                                                 const float* __restrict__ Wq,
                                                 const float* __restrict__ Wk,
                                                 unsigned short* __restrict__ qg,
                                                 unsigned short* __restrict__ kg) {
    __shared__ float xs[16][D_];
    const int rbase = blockIdx.x * 16;
    const float4* xsrc = (const float4*)(x + (size_t)rbase * D_);
    float4* xdst = (float4*)&xs[0][0];
    for (int i = threadIdx.x; i < 16 * D_ / 4; i += 256) xdst[i] = xsrc[i];
    __syncthreads();

    const int c  = threadIdx.x & 127;
    const int rg = threadIdx.x >> 7;
    const float* __restrict__ W = (c < 64) ? Wq : Wk;
    const int u = c & 63;

    float acc[8] = {0.f, 0.f, 0.f, 0.f, 0.f, 0.f, 0.f, 0.f};
    #pragma unroll 4
    for (int d = 0; d < D_; ++d) {
        const float wv = W[d * U_ + u];
        #pragma unroll
        for (int r = 0; r < 8; ++r) acc[r] = fmaf(xs[rg * 8 + r][d], wv, acc[r]);
    }

    const int m  = u >> 4;
    const int b3 = (u >> 3) & 1;
    const int e  = u & 7;
    const int row0 = rbase + rg * 8;
    unsigned short* dst = ((c < 64) ? qg : kg)
        + (size_t)(row0 >> 5) * QK_TILE
        + ((m * 64) + (row0 & 31) + 32 * b3) * 8 + e;
    #pragma unroll
    for (int r = 0; r < 8; ++r) dst[r * 8] = f2bf(acc[r]);
}

// ---------------- kernel 3: x -> xT B-fragments, per (b, key-tile) ----------------
__global__ __launch_bounds__(512) void xpose_k(const float* __restrict__ x,
                                               unsigned short* __restrict__ xTg) {
    __shared__ float xs[TK][D_ + 4];
    const int tid = threadIdx.x;
    const int bt  = blockIdx.x;             // b*128 + kt
    const int s0  = (bt & 127) * TK;
    const int b   = bt >> 7;
    const float* xsrc = x + ((size_t)(b * S_ + s0)) * D_;
    const int r_ = tid >> 4, c_ = tid & 15;
    #pragma unroll
    for (int it = 0; it < 12; ++it) {
        const int col4 = c_ + it * 16;
        *(float4*)&xs[r_][col4 * 4] = *(const float4*)&xsrc[(size_t)r_ * D_ + col4 * 4];
    }
    __syncthreads();

    unsigned short* dst = xTg + (size_t)bt * XT_TILE;
    #pragma unroll
    for (int it = 0; it < 6; ++it) {
        const int cch = it * 512 + tid;
        const int col = cch & 31;
        const int kh  = (cch >> 5) & 1;
        const int db  = (cch >> 6) % 24;
        const int kw  = (cch >> 6) / 24;
        const int d   = db * 32 + col;
        const int sr  = kw * 16 + kh * 8;
        short8 v;
        #pragma unroll
        for (int e = 0; e < 8; ++e) v[e] = (short)f2bf(xs[sr + e][d]);
        *(short8*)&dst[cch * 8] = v;
    }
}

// ------- kernel 4: wave-autonomous flash, software-pipelined, straight-line body -------
// wave = (qtile 32q, dg 192d). iter: QK(t)+PV(t-1) MFMAs issue together; softmax(t)
// on VALU overlaps matrix pipe; xv(t)/k(t+1) reload covered by next iteration.
// NO lambdas: aggregates (acc, xvp, c_) stay SROA-promotable -> registers (R12 lesson).
__global__ __launch_bounds__(512, 2) void attn_k(const unsigned short* __restrict__ xTg,
                                                 const unsigned short* __restrict__ qg,
                                                 const unsigned short* __restrict__ kg,
                                                 const float* __restrict__ maskf,
                                                 const float* __restrict__ biasf,
                                                 float* __restrict__ out) {
    __shared__ float sc_l[8][32];                            // per-wave rescale broadcast
    __shared__ __align__(16) unsigned short p_l[8][1024];    // per-wave p A-frags (2KB)

    const int tid = threadIdx.x;
    const int w = tid >> 6;
    const int l = tid & 63;
    const int hi = l >> 5;
    const int q5 = l & 31;
    // XCD remap: raw&7 -> (b, parity); each XCD's 32 blocks share one batch's xT
    // stream and march in rough lockstep from t0 = par*64.
    const int raw = blockIdx.x;
    const int bh = raw & 7;
    const int b = bh >> 1;
    const int par = bh & 1;
    const int qpair = (raw >> 3) * 2 + par;      // 0..63
    const int qtile = qpair * 2 + (w >> 2);      // 0..127
    const int dg = w & 3;
    const int bS = b * S_;
    const int q0 = qtile * 32;
    const int t0 = par * 64;

    const unsigned short* xT_b = xTg + (size_t)b * NT * XT_TILE;
    const unsigned short* kg_b = kg + (size_t)(b * NT) * QK_TILE;
    const float* bias_b = biasf + bS;
    unsigned short* pw = &p_l[w][0];

    // Q B-fragments (held whole kernel)
    short8 qf[4];
    {
        const unsigned short* qp = qg + (size_t)(b * NT + qtile) * QK_TILE;
        #pragma unroll
        for (int m = 0; m < 4; ++m) qf[m] = *(const short8*)(qp + (m * 64 + l) * 8);
    }

    f32x16 acc[6];
    {
        f32x16 z = {0.f};
        #pragma unroll
        for (int j = 0; j < 6; ++j) acc[j] = z;
    }
    float m_run = -1e30f, l_run = 0.f;

    // pipeline state (plain locals, static indexing only)
    short8 xvp[12];
    short8 pf0p = {0}, pf1p = {0};
    short8 kfA[4], kfB[4];

#define MSK (NT - 1)

#define LOAD_K(kdst, tn)                                                              \
    {                                                                                 \
        const unsigned short* kp_ = kg_b + (size_t)(tn) * QK_TILE;                    \
        _Pragma("unroll")                                                             \
        for (int m_ = 0; m_ < 4; ++m_) kdst[m_] = *(const short8*)(kp_ + (m_ * 64 + l) * 8); \
    }

#define LOAD_XV(tt)                                                                   \
    {                                                                                 \
        const unsigned short* xt_ = xT_b + (size_t)(tt) * XT_TILE;                    \
        _Pragma("unroll")                                                             \
        for (int kw_ = 0; kw_ < 2; ++kw_)                                             \
            _Pragma("unroll")                                                         \
            for (int j_ = 0; j_ < 6; ++j_)                                            \
                xvp[kw_ * 6 + j_] =                                                   \
                    *(const short8*)(xt_ + ((kw_ * 24 + dg * 6 + j_) * 64 + l) * 8);  \
    }

#define PV()                                                                          \
    {                                                                                 \
        _Pragma("unroll")                                                             \
        for (int j_ = 0; j_ < 6; ++j_) {                                              \
            acc[j_] = __builtin_amdgcn_mfma_f32_32x32x16_bf16(pf0p, xvp[j_], acc[j_], 0, 0, 0);     \
            acc[j_] = __builtin_amdgcn_mfma_f32_32x32x16_bf16(pf1p, xvp[6 + j_], acc[j_], 0, 0, 0); \
        }                                                                             \
    }

#define SOFTMAX_PACK(tt, cvar)                                                        \
    {                                                                                 \
        const float* bt_ = bias_b + (tt) * TK;                                        \
        float4 b4_[4];                                                                \
        _Pragma("unroll")                                                             \
        for (int g_ = 0; g_ < 4; ++g_) b4_[g_] = *(const float4*)(bt_ + g_ * 8 + hi * 4); \
        float s_[16];                                                                 \
        _Pragma("unroll")                                                             \
        for (int r_ = 0; r_ < 16; ++r_)                                               \
            s_[r_] = fmaf(cvar[r_], 0.125f, ((const float*)&b4_[r_ >> 2])[r_ & 3]);   \
        float mx_ = s_[0];                                                            \
        _Pragma("unroll")                                                             \
        for (int r_ = 1; r_ < 16; ++r_) mx_ = fmaxf(mx_, s_[r_]);                     \
        mx_ = fmaxf(mx_, __shfl_xor(mx_, 32));                                        \
        const bool upd_ = (mx_ > m_run + 8.f);   /* defer-max (T13) */                \
        if (__any(upd_)) {                                                            \
            float sc_ = 1.f;                                                          \
            if (upd_) { sc_ = __expf(m_run - mx_); m_run = mx_; }                     \
            l_run *= sc_;                                                             \
            if (!hi) sc_l[w][q5] = sc_;                                               \
            float4 scv_[4];                                                           \
            _Pragma("unroll")                                                         \
            for (int g_ = 0; g_ < 4; ++g_) scv_[g_] = *(const float4*)&sc_l[w][g_ * 8 + hi * 4]; \
            _Pragma("unroll")                                                         \
            for (int j_ = 0; j_ < 6; ++j_)                                            \
                _Pragma("unroll")                                                     \
                for (int r_ = 0; r_ < 16; ++r_)                                       \
                    acc[j_][r_] *= ((const float*)&scv_[r_ >> 2])[r_ & 3];            \
        }                                                                             \
        float p_[16], ps_ = 0.f;                                                      \
        _Pragma("unroll")                                                             \
        for (int r_ = 0; r_ < 16; ++r_) { p_[r_] = __expf(s_[r_] - m_run); ps_ += p_[r_]; } \
        ps_ += __shfl_xor(ps_, 32);                                                   \
        l_run += ps_;                                                                 \
        _Pragma("unroll")                                                             \
        for (int j_ = 0; j_ < 8; ++j_) {                                              \
            const int r_ = j_ * 2;                                                    \
            const unsigned int pk_ =                                                  \
                (unsigned int)f2bf(p_[r_]) | ((unsigned int)f2bf(p_[r_ + 1]) << 16);  \
            const int mm_ = r_ >> 3;                                                  \
            const int lp_ = q5 + 32 * ((r_ >> 2) & 1);                                \
            const int by_ = ((r_ & 3) + 4 * hi) * 2;                                  \
            *(unsigned int*)((char*)pw + mm_ * 1024 + lp_ * 16 + by_) = pk_;          \
        }                                                                             \
        pf0p = *(const short8*)(pw + l * 8);                                          \
        pf1p = *(const short8*)(pw + 512 + l * 8);                                    \
    }

// body for tile tt: QK(tt) + PV(tt-1) issue together; reload xv/k; softmax(tt)
#define BODY(tt, tn, kcur, knxt)                                                      \
    {                                                                                 \
        f32x16 c_ = {0.f};                                                            \
        _Pragma("unroll")                                                             \
        for (int m_ = 0; m_ < 4; ++m_)                                                \
            c_ = __builtin_amdgcn_mfma_f32_32x32x16_bf16(kcur[m_], qf[m_], c_, 0, 0, 0); \
        PV();                                                                         \
        LOAD_XV(tt);                                                                  \
        LOAD_K(knxt, tn);                                                             \
        SOFTMAX_PACK(tt, c_);                                                         \
    }

    // ---- prologue: softmax(t0), no PV pending ----
    LOAD_K(kfA, t0);
    {
        f32x16 c_ = {0.f};
        #pragma unroll
        for (int m_ = 0; m_ < 4; ++m_)
            c_ = __builtin_amdgcn_mfma_f32_32x32x16_bf16(kfA[m_], qf[m_], c_, 0, 0, 0);
        SOFTMAX_PACK(t0, c_);
    }
    LOAD_XV(t0);
    LOAD_K(kfB, (t0 + 1) & MSK);

    for (int it = 1; it + 1 < NT; it += 2) {
        BODY((t0 + it) & MSK, (t0 + it + 1) & MSK, kfB, kfA);
        BODY((t0 + it + 1) & MSK, (t0 + it + 2) & MSK, kfA, kfB);
    }
    BODY((t0 + NT - 1) & MSK, t0, kfB, kfA);   // tile 127 (prefetch wraps, harmless)
    PV();                                       // drain PV(last)

#undef BODY
#undef SOFTMAX_PACK
#undef PV
#undef LOAD_XV
#undef LOAD_K
#undef MSK

    // ---------- epilogue: inv broadcast, q-mask, store ----------
    {
        const float mq = maskf[bS + q0 + q5];
        const float inv = (mq > 0.f && l_run > 0.f) ? (1.f / l_run) : 0.f;
        if (!hi) sc_l[w][q5] = inv;
        float4 iv[4];
        #pragma unroll
        for (int g = 0; g < 4; ++g) iv[g] = *(const float4*)&sc_l[w][g * 8 + hi * 4];
        #pragma unroll
        for (int j = 0; j < 6; ++j) {
            const int dcol = dg * 192 + j * 32 + q5;
            #pragma unroll
            for (int r = 0; r < 16; ++r) {
                const int qr = (r & 3) + 8 * (r >> 2) + 4 * hi;
                out[(size_t)(bS + q0 + qr) * D_ + dcol] = acc[j][r] * ((const float*)&iv[r >> 2])[r & 3];
            }
        }
    }
}

extern "C" void kernel_launch(void* const* d_in, const int* in_sizes, int n_in,
                              void* d_out, int out_size, void* d_ws, size_t ws_size,
                              hipStream_t stream) {
    const float*         x    = (const float*)d_in[0];
    const unsigned char* mraw = (const unsigned char*)d_in[1];
    const float*         Wq   = (const float*)d_in[2];
    const float*         Wk   = (const float*)d_in[3];
    float*               outp = (float*)d_out;

    // ws: maskf f32 | biasf f32 | qg bf16 | kg bf16 | xTg bf16  (~28.1 MB)
    float* maskf = (float*)d_ws;
    float* biasf = maskf + (size_t)B_ * S_;
    unsigned short* qg  = (unsigned short*)(biasf + (size_t)B_ * S_);
    unsigned short* kg  = qg + (size_t)B_ * S_ * U_;
    unsigned short* xTg = kg + (size_t)B_ * S_ * U_;

    decode_mask_k<<<(B_ * S_) / 256, 256, 0, stream>>>(mraw, maskf, biasf);
    proj_qk_k<<<(B_ * S_) / 16, 256, 0, stream>>>(x, Wq, Wk, qg, kg);
    xpose_k<<<B_ * (S_ / TK), 512, 0, stream>>>(x, xTg);
    attn_k<<<256, 512, 0, stream>>>(xTg, qg, kg, maskf, biasf, outp);
}